// Round 3
// baseline (10084.460 us; speedup 1.0000x reference)
//
#include <hip/hip_runtime.h>
#include <stdint.h>

#define Bsz  128
#define NUMS 128
#define SEQn 256
#define Hn   1024
#define PRED 96
#define G4H  4096
#define GN   128            // persistent grid: 128 blocks = 64 nb x 2 mb
#define BH   ((size_t)Bsz*Hn)

typedef __attribute__((ext_vector_type(8))) short bf16x8;
typedef __attribute__((ext_vector_type(4))) float f32x4;

__device__ __forceinline__ unsigned short f2bf(float x){
  union { float f; unsigned u; } v; v.f = x;
  return (unsigned short)((v.u + 0x7FFFu + ((v.u >> 16) & 1u)) >> 16);
}
__device__ __forceinline__ float bf2f(unsigned short s){
  union { unsigned u; float f; } v; v.u = ((unsigned)s) << 16; return v.f;
}

// ---- pack x: [B][NUMS][SEQ] f32 -> xp [SEQ][B][NUMS] bf16 (LDS transpose) ----
__global__ void pack_x_kernel(const float* __restrict__ x, unsigned short* __restrict__ xp){
  __shared__ float tile[64][65];
  const int t0 = blockIdx.x * 64, n0 = blockIdx.y * 64, b = blockIdx.z;
  const int tid = threadIdx.x;
  const int c = tid & 63, r = tid >> 6;
  #pragma unroll
  for (int i = 0; i < 16; i++){
    int n = r + i*4;
    tile[n][c] = x[((size_t)b*NUMS + n0 + n)*SEQn + t0 + c];
  }
  __syncthreads();
  #pragma unroll
  for (int i = 0; i < 16; i++){
    int t = r + i*4;
    xp[((size_t)(t0+t)*Bsz + b)*NUMS + n0 + c] = f2bf(tile[c][t]);
  }
}

// ---- pack W rows into MFMA B-frag order: [cgg][kst][lane][8] ----
__global__ void pack_w_kernel(const float* __restrict__ W, unsigned short* __restrict__ Wpk,
                              int KST, int row_off, int gate_il){
  const int u = blockIdx.x * blockDim.x + threadIdx.x;
  if (u >= 256*KST*64) return;
  const int lane = u & 63;
  const int kst  = (u >> 6) % KST;
  const int cgg  = (u >> 6) / KST;
  int col;
  if (gate_il){ const int nb = cgg >> 2, gate = cgg & 3; col = gate*Hn + nb*16 + (lane & 15); }
  else        { col = cgg*16 + (lane & 15); }
  const int kbase = row_off + kst*32 + (lane >> 4)*8;
  unsigned short tmp[8];
  #pragma unroll
  for (int e = 0; e < 8; e++) tmp[e] = f2bf(W[(size_t)(kbase+e)*G4H + col]);
  ((ulonglong2*)Wpk)[u] = *(const ulonglong2*)tmp;
}

__global__ void zero_kernel(unsigned short* __restrict__ h0, float* __restrict__ c,
                            unsigned* __restrict__ bars){
  int i = blockIdx.x*256 + threadIdx.x;
  if (i < Bsz*Hn){ h0[i] = 0; c[i] = 0.0f; }
  if (i < 512) bars[i] = 0u;
}

// ---- persistent LSTM layer. grid = GN = 128 blocks (64 nb x 2 mb, M=64 rows/block),
// 512 thr = 8 waves = 4 gate-groups x 2 row-halves. All blocks resident (<=1/CU).
// LAYER=0: A=[xp_t | h0_{t-1}] (K=1152); h0 ring slots 0..256, write slot t+1.
//          Every ring address: one sc1 write, later plain reads only -> stale-free.
// LAYER=1: A=[h0_t (ring slot t+1, plain) | h1_{t-1}]. h1 lives in h1b:
//          RING2=1: write-once ring slots 0..255 (plain reads);
//          RING2=0: 2-slot ping-pong, reads aux=17 (sc0|sc1 -> L3, dodge stale L2).
// Grid barrier between steps: entry __syncthreads drains sc1 h-publishes (vmcnt0),
// then fetch_add; NEXT-STEP A1 (h0 ring: written by the PREVIOUS KERNEL, stable)
// is prefetch-issued between add and spin so its latency hides under the spin.
// c state lives in 2 registers per thread across all 256 steps.
template<int K1, int KTOT, int LAYER, bool RING2>
__global__ __launch_bounds__(512, 1)
void persist_kernel(const unsigned short* __restrict__ xpp,
                    unsigned short* __restrict__ hring,
                    unsigned short* __restrict__ h1b,
                    const unsigned short* __restrict__ Wpk,
                    const float* __restrict__ bias,
                    float* __restrict__ cst,
                    float* __restrict__ hf_out,
                    unsigned* __restrict__ bar)
{
  constexpr int KST_TOT = KTOT/32;
  constexpr int NCH = (KTOT + 255)/256;
  __shared__ union SM {
    unsigned short a[2][64*256];      // 2 x 32KB chunk buffers (64 rows x 256 cols bf16)
    float e[4*64*18];                 // epilogue gate tile overlay (18KB)
  } sm;
  const int tid = threadIdx.x;
  const int w = tid >> 6, l = tid & 63;
  const int blk = blockIdx.x;
  const int q = blk >> 3;
  const int nb = (blk & 7)*8 + (q & 7);   // XCD (blk&7) owns 8 consecutive nb -> W slice L2-resident
  const int mb = q >> 3;                  // 0..1, 64 rows each
  const int mf = w & 1, cgi = w >> 1;     // row-half, gate index
  const int cgg = nb*4 + cgi;
  const int lrow = l & 15, lg = l >> 4;

  // fixed per-thread epilogue elements (2 rows), c in registers across steps
  const int erow = tid >> 4, ejj = tid & 15;
  const int J = nb*16 + ejj;
  const int R0 = mb*64 + erow, R1 = R0 + 32;
  const size_t idx0 = (size_t)R0*Hn + J, idx1 = (size_t)R1*Hn + J;
  float c0 = (LAYER == 0) ? 0.f : cst[idx0];
  float c1 = (LAYER == 0) ? 0.f : cst[idx1];

  for (int t = 0; t < SEQn; ++t){
    const unsigned short* A1;
    const unsigned short* A2;
    unsigned short* hout;
    if (LAYER == 0){
      A1   = xpp + (size_t)t*Bsz*NUMS;
      A2   = hring + (size_t)t*BH;
      hout = hring + (size_t)(t+1)*BH;
    } else {
      A1   = hring + (size_t)(t+1)*BH;                       // h0_t (prev kernel's output)
      A2   = (t == 0) ? (hring + (size_t)SEQn*BH)
                      : (h1b + (size_t)(RING2 ? (t-1) : ((t-1)&1))*BH);
      hout = h1b + (size_t)(RING2 ? t : (t&1))*BH;
    }

    f32x4 acc[2] = {{0.f,0.f,0.f,0.f},{0.f,0.f,0.f,0.f}};

    auto stage = [&](int bb, int ch, int kw, int lu,
                     const unsigned short* A1p, const unsigned short* A2p){
      const int nissue = kw >> 3;           // (64 rows * kw cols * 2B) / 1024B
      for (int i = w; i < nissue; i += 8){
        const int s = i*64 + l;
        const int row = s >> lu;
        const int uu  = s & ((1 << lu) - 1);
        const int ku  = uu ^ (row & 7);
        const int kg  = ch*256 + ku*8;
        const int Rr  = mb*64 + row;
        if (kg < K1){
          const unsigned short* src = A1p + (size_t)Rr*K1 + kg;
          __builtin_amdgcn_global_load_lds(
            (const __attribute__((address_space(1))) void*)src,
            (__attribute__((address_space(3))) void*)&sm.a[bb][i*512], 16, 0, 0);
        } else {
          const unsigned short* src = A2p + (size_t)Rr*Hn + (kg - K1);
          if constexpr (LAYER == 1 && !RING2){
            __builtin_amdgcn_global_load_lds(   // h1 ping-pong: L3-coherent read
              (const __attribute__((address_space(1))) void*)src,
              (__attribute__((address_space(3))) void*)&sm.a[bb][i*512], 16, 0, 17);
          } else {
            __builtin_amdgcn_global_load_lds(
              (const __attribute__((address_space(1))) void*)src,
              (__attribute__((address_space(3))) void*)&sm.a[bb][i*512], 16, 0, 0);
          }
        }
      }
    };

    const bool pre = (LAYER == 1) && (t > 0);   // chunks 0,1 were issued inside prev barrier
    if (!pre) stage(0, 0, 256, 5, A1, A2);
    __syncthreads();

    #pragma unroll
    for (int ch = 0; ch < NCH; ch++){
      const int bb = ch & 1;
      const int kw = ((KTOT - ch*256) >= 256) ? 256 : (KTOT - ch*256);
      if (ch + 1 < NCH && !(pre && ch == 0)){
        const int kwn = ((KTOT - (ch+1)*256) >= 256) ? 256 : (KTOT - (ch+1)*256);
        stage(bb ^ 1, ch+1, kwn, (kwn == 256) ? 5 : 4, A1, A2);
      }
      const int UPR  = kw >> 3;
      const int kstc = kw >> 5;
      const unsigned short* wp = Wpk + ((size_t)(cgg*KST_TOT + ch*8)*64 + l)*8;
      #pragma unroll
      for (int ks = 0; ks < kstc; ks++){
        const int unit = ks*4 + lg;
        bf16x8 bw = *(const bf16x8*)(wp + (size_t)ks*512);
        #pragma unroll
        for (int mi = 0; mi < 2; mi++){
          const int arow = mf*32 + mi*16 + lrow;
          bf16x8 af = *(const bf16x8*)&sm.a[bb][(arow*UPR + (unit ^ (arow & 7)))*8];
          acc[mi] = __builtin_amdgcn_mfma_f32_16x16x32_bf16(af, bw, acc[mi], 0, 0, 0);
        }
      }
      __syncthreads();
    }

    {
      const int jj = l & 15;
      #pragma unroll
      for (int mi = 0; mi < 2; mi++)
        #pragma unroll
        for (int r = 0; r < 4; r++){
          const int row2 = mf*32 + mi*16 + lg*4 + r;
          sm.e[(cgi*64 + row2)*18 + jj] = acc[mi][r];
        }
    }
    __syncthreads();
    {
      #pragma unroll
      for (int half = 0; half < 2; half++){
        const int row = erow + half*32;
        float zi = sm.e[(0*64+row)*18 + ejj];
        float zf = sm.e[(1*64+row)*18 + ejj];
        float zo = sm.e[(2*64+row)*18 + ejj];
        float zg = sm.e[(3*64+row)*18 + ejj];
        zi += bias[0*Hn + J]; zf += bias[1*Hn + J];
        zo += bias[2*Hn + J]; zg += bias[3*Hn + J];
        const float gi = 1.f/(1.f + __expf(-zi));
        const float gf = 1.f/(1.f + __expf(-zf));
        const float go = 1.f/(1.f + __expf(-zo));
        const float gg = tanhf(zg);
        float& cr = half ? c1 : c0;
        cr = gf * cr + gi * gg;
        const float hn = go * tanhf(cr);
        const size_t idx = half ? idx1 : idx0;
        // publish h at agent scope (sc1 -> L3), packed 2x bf16 per dword
        const unsigned hu   = (unsigned)f2bf(hn);
        const unsigned mate = (unsigned)__shfl_xor((int)hu, 1);
        if ((l & 1) == 0){
          const unsigned pk = hu | (mate << 16);
          __hip_atomic_store((unsigned*)(hout + idx), pk,
                             __ATOMIC_RELAXED, __HIP_MEMORY_SCOPE_AGENT);
        }
        if (t == SEQn-1){
          cst[idx] = cr;                 // layer handoff / final output (kernel boundary)
          if (LAYER == 1) hf_out[idx] = hn;
        }
      }
    }

    if (t + 1 < SEQn){
      // ---- grid barrier with in-barrier prefetch ----
      __syncthreads();                   // drains vmcnt: all h-publishes at L3; sm free
      if (tid == 0)
        __hip_atomic_fetch_add(&bar[t], 1u, __ATOMIC_RELAXED, __HIP_MEMORY_SCOPE_AGENT);
      if constexpr (LAYER == 1){
        // next step's A1 = h0 ring slot t+2: written by the PREVIOUS kernel -> stable,
        // safe to read before the barrier resolves. Latency hides under the spin.
        const unsigned short* A1n = hring + (size_t)(t+2)*BH;
        stage(0, 0, 256, 5, A1n, A1n);   // kg<K1 always for ch0,1: A2 arg unused
        stage(1, 1, 256, 5, A1n, A1n);
      }
      if (tid == 0){
        while (__hip_atomic_load(&bar[t], __ATOMIC_RELAXED, __HIP_MEMORY_SCOPE_AGENT) < GN)
          __builtin_amdgcn_s_sleep(1);
      }
      __syncthreads();                   // exit: also drains the prefetch issued above
    }
  }
}

// ---- final FC + copy h,c to d_out ----
__global__ __launch_bounds__(256)
void fc_out_kernel(const float* __restrict__ hf, const float* __restrict__ cst,
                   const float* __restrict__ fcw, const float* __restrict__ fcb,
                   float* __restrict__ dout){
  __shared__ float hrow[Hn];
  const int b = blockIdx.x, tid = threadIdx.x;
  for (int i = tid; i < Hn; i += 256) hrow[i] = hf[(size_t)b*Hn + i];
  __syncthreads();
  if (tid < PRED){
    float a = fcb[tid];
    for (int k = 0; k < Hn; k++) a += hrow[k] * fcw[(size_t)k*PRED + tid];
    dout[(size_t)b*PRED + tid] = tanhf(a);
  }
  for (int i = tid; i < Hn; i += 256){
    dout[Bsz*PRED + (size_t)b*Hn + i] = hf[(size_t)b*Hn + i];
    dout[Bsz*PRED + (size_t)Bsz*Hn + (size_t)b*Hn + i] = cst[(size_t)b*Hn + i];
  }
}

extern "C" void kernel_launch(void* const* d_in, const int* in_sizes, int n_in,
                              void* d_out, int out_size, void* d_ws, size_t ws_size,
                              hipStream_t stream){
  const float* x   = (const float*)d_in[0];
  const float* W0  = (const float*)d_in[1];
  const float* b0  = (const float*)d_in[2];
  const float* W1  = (const float*)d_in[3];
  const float* b1  = (const float*)d_in[4];
  const float* fcw = (const float*)d_in[5];
  const float* fcb = (const float*)d_in[6];
  float* dout = (float*)d_out;

  char* p = (char*)d_ws;
  auto alloc = [&](size_t bytes)->void*{
    void* r = (void*)p; p += (bytes + 255) & ~(size_t)255; return r;
  };
  // base footprint ~103 MB (proven to fit)
  unsigned short* xp   = (unsigned short*)alloc((size_t)SEQn*Bsz*NUMS*2);      // 8.4 MB
  unsigned short* Wpk0 = (unsigned short*)alloc((size_t)256*36*64*8*2);        // 9.4 MB
  unsigned short* Wpk1 = (unsigned short*)alloc((size_t)256*64*64*8*2);        // 16.8 MB
  unsigned short* H0   = (unsigned short*)alloc((size_t)(SEQn+1)*BH*2);        // 67.4 MB
  float* cst = (float*)alloc((size_t)BH*4);                                    // 0.5 MB
  float* hf  = (float*)alloc((size_t)BH*4);                                    // 0.5 MB
  unsigned* bars = (unsigned*)alloc((size_t)512*sizeof(unsigned));             // 2 KB

  const bool big = ws_size >= (size_t)180*1024*1024;   // room for a write-once h1 ring?
  unsigned short* h1b;
  if (big) h1b = (unsigned short*)alloc((size_t)SEQn*BH*2);                    // 67.1 MB
  else     h1b = (unsigned short*)alloc((size_t)2*BH*2);                       // 0.5 MB

  pack_x_kernel<<<dim3(SEQn/64, NUMS/64, Bsz), dim3(256), 0, stream>>>(x, xp);
  pack_w_kernel<<<dim3((256*36*64 + 255)/256), dim3(256), 0, stream>>>(W0, Wpk0, 36, 0, 1);
  pack_w_kernel<<<dim3((256*64*64 + 255)/256), dim3(256), 0, stream>>>(W1, Wpk1, 64, 0, 1);
  zero_kernel<<<dim3((Bsz*Hn + 255)/256), dim3(256), 0, stream>>>(H0, cst, bars);

  // layer 0: ONE persistent launch, 256 grid-barriered steps (K = 128 + 1024)
  persist_kernel<128, 1152, 0, false><<<dim3(GN), dim3(512), 0, stream>>>(
      xp, H0, nullptr, Wpk0, b0, cst, nullptr, bars);

  // layer 1: ONE persistent launch (K = 1024 + 1024); h1 in ring (big) or ping-pong
  if (big){
    persist_kernel<1024, 2048, 1, true><<<dim3(GN), dim3(512), 0, stream>>>(
        nullptr, H0, h1b, Wpk1, b1, cst, hf, bars + 256);
  } else {
    persist_kernel<1024, 2048, 1, false><<<dim3(GN), dim3(512), 0, stream>>>(
        nullptr, H0, h1b, Wpk1, b1, cst, hf, bars + 256);
  }

  fc_out_kernel<<<dim3(Bsz), dim3(256), 0, stream>>>(hf, cst, fcw, fcb, dout);
}

// Round 4
// 5861.167 us; speedup vs baseline: 1.7206x; 1.7206x over previous
//
#include <hip/hip_runtime.h>
#include <stdint.h>

#define Bsz  128
#define NUMS 128
#define SEQn 256
#define Hn   1024
#define PRED 96
#define G4H  4096
#define GN   256            // persistent grid: 256 blocks = 64 nb x 4 mb (1 per CU)
#define BH   ((size_t)Bsz*Hn)

typedef __attribute__((ext_vector_type(8))) short bf16x8;
typedef __attribute__((ext_vector_type(4))) float f32x4;

__device__ __forceinline__ unsigned short f2bf(float x){
  union { float f; unsigned u; } v; v.f = x;
  return (unsigned short)((v.u + 0x7FFFu + ((v.u >> 16) & 1u)) >> 16);
}
__device__ __forceinline__ float bf2f(unsigned short s){
  union { unsigned u; float f; } v; v.u = ((unsigned)s) << 16; return v.f;
}

// ---- pack x: [B][NUMS][SEQ] f32 -> xp [SEQ][B][NUMS] bf16 (LDS transpose) ----
__global__ void pack_x_kernel(const float* __restrict__ x, unsigned short* __restrict__ xp){
  __shared__ float tile[64][65];
  const int t0 = blockIdx.x * 64, n0 = blockIdx.y * 64, b = blockIdx.z;
  const int tid = threadIdx.x;
  const int c = tid & 63, r = tid >> 6;
  #pragma unroll
  for (int i = 0; i < 16; i++){
    int n = r + i*4;
    tile[n][c] = x[((size_t)b*NUMS + n0 + n)*SEQn + t0 + c];
  }
  __syncthreads();
  #pragma unroll
  for (int i = 0; i < 16; i++){
    int t = r + i*4;
    xp[((size_t)(t0+t)*Bsz + b)*NUMS + n0 + c] = f2bf(tile[c][t]);
  }
}

// ---- pack W rows into MFMA B-frag order: [cgg][kst][lane][8] ----
__global__ void pack_w_kernel(const float* __restrict__ W, unsigned short* __restrict__ Wpk,
                              int KST, int row_off, int gate_il){
  const int u = blockIdx.x * blockDim.x + threadIdx.x;
  if (u >= 256*KST*64) return;
  const int lane = u & 63;
  const int kst  = (u >> 6) % KST;
  const int cgg  = (u >> 6) / KST;
  int col;
  if (gate_il){ const int nb = cgg >> 2, gate = cgg & 3; col = gate*Hn + nb*16 + (lane & 15); }
  else        { col = cgg*16 + (lane & 15); }
  const int kbase = row_off + kst*32 + (lane >> 4)*8;
  unsigned short tmp[8];
  #pragma unroll
  for (int e = 0; e < 8; e++) tmp[e] = f2bf(W[(size_t)(kbase+e)*G4H + col]);
  ((ulonglong2*)Wpk)[u] = *(const ulonglong2*)tmp;
}

__global__ void zero_kernel(unsigned short* __restrict__ h0, float* __restrict__ c,
                            unsigned* __restrict__ bars){
  int i = blockIdx.x*256 + threadIdx.x;
  if (i < Bsz*Hn){ h0[i] = 0; c[i] = 0.0f; }
  if (i < 512) bars[i] = 0u;
}

// ---- persistent LSTM layer, W RESIDENT IN REGISTERS across all 256 steps ----
// grid = 256 blocks (1/CU), 512 thr = 8 waves. Block tile: 32 rows (mb) x 64 cols (nb),
// 4 gates. Wave w: cgi = w>>1 (gate), ksh = w&1 (K parity). Each wave holds the W frags
// for its cgg at kst % 2 == ksh: KST_TOT/2 x bf16x8 (72 VGPR L0 / 128 VGPR L1) -> the
// inner loop has ZERO global W loads (this was the serial-L2-latency bottleneck: ~500cy
// x KTOT/32 per step in rounds 2-3).
// LAYER=0: A=[xp_t | h0_{t-1}] (K=1152); h0 ring slots 0..256, write slot t+1 (sc1).
// LAYER=1: A=[h0_t (ring slot t+1, plain) | h1_{t-1}]; h1 in write-once ring (RING2) or
//          2-slot ping-pong read with aux=17 (L3-coherent). In-barrier prefetch of the
//          next step's h0 chunks (stable data) hides their latency under the spin.
// c lives in ONE register per thread across all 256 steps.
template<int K1, int KTOT, int LAYER, bool RING2>
__global__ __launch_bounds__(512, 2)
void persist_kernel(const unsigned short* __restrict__ xpp,
                    unsigned short* __restrict__ hring,
                    unsigned short* __restrict__ h1b,
                    const unsigned short* __restrict__ Wpk,
                    const float* __restrict__ bias,
                    float* __restrict__ cst,
                    float* __restrict__ hf_out,
                    unsigned* __restrict__ bar)
{
  constexpr int KST_TOT = KTOT/32;
  constexpr int HALF = KST_TOT/2;
  constexpr int NCH = (KTOT + 511)/512;
  __shared__ union SM {
    unsigned short a[2][32*512];    // 2 x 32KB A-chunk buffers (32 rows x 512 cols bf16)
    float e[2][4*32*18];            // epilogue partials [ksh][gate*32+row][16+pad]
  } sm;
  const int tid = threadIdx.x;
  const int w = tid >> 6, l = tid & 63;
  const int blk = blockIdx.x;
  const int q = blk >> 3;
  const int nb = (blk & 7)*8 + (q & 7);   // XCD (blk&7) owns 8 consecutive nb
  const int mb = q >> 3;                  // 0..3, 32 rows each
  const int ksh = w & 1, cgi = w >> 1;    // K-parity, gate
  const int cgg = nb*4 + cgi;
  const int lrow = l & 15, lg = l >> 4;

  // ---- W -> registers, once ----
  bf16x8 wreg[HALF];
  #pragma unroll
  for (int j = 0; j < HALF; j++)
    wreg[j] = *(const bf16x8*)(Wpk + ((size_t)(cgg*KST_TOT + 2*j + ksh)*64 + l)*8);

  // fixed per-thread epilogue element; c stays in a register across steps
  const int erow = tid >> 4, ejj = tid & 15;
  const int R = mb*32 + erow;
  const int J = nb*16 + ejj;
  const size_t idx = (size_t)R*Hn + J;
  float creg = (LAYER == 0) ? 0.f : cst[idx];

  for (int t = 0; t < SEQn; ++t){
    const unsigned short* A1;
    const unsigned short* A2;
    unsigned short* hout;
    if (LAYER == 0){
      A1   = xpp + (size_t)t*Bsz*NUMS;
      A2   = hring + (size_t)t*BH;
      hout = hring + (size_t)(t+1)*BH;
    } else {
      A1   = hring + (size_t)(t+1)*BH;                       // h0_t (prev kernel output)
      A2   = (t == 0) ? (hring + (size_t)SEQn*BH)
                      : (h1b + (size_t)(RING2 ? (t-1) : ((t-1)&1))*BH);
      hout = h1b + (size_t)(RING2 ? t : (t&1))*BH;
    }

    f32x4 acc2[2] = {{0.f,0.f,0.f,0.f},{0.f,0.f,0.f,0.f}};

    auto stage = [&](int bb, int ch, int kw, int lu,
                     const unsigned short* A1p, const unsigned short* A2p){
      const int nissue = kw >> 4;                 // (32 rows * kw * 2B) / 1024B
      for (int i = w; i < nissue; i += 8){
        const int s = i*64 + l;
        const int row = s >> lu;
        const int uu  = s & ((1 << lu) - 1);
        const int ku  = uu ^ (row & 7);
        const int kg  = ch*512 + ku*8;
        const int Rr  = mb*32 + row;
        if (kg < K1){
          const unsigned short* src = A1p + (size_t)Rr*K1 + kg;
          __builtin_amdgcn_global_load_lds(
            (const __attribute__((address_space(1))) void*)src,
            (__attribute__((address_space(3))) void*)&sm.a[bb][i*512], 16, 0, 0);
        } else {
          const unsigned short* src = A2p + (size_t)Rr*Hn + (kg - K1);
          if constexpr (LAYER == 1 && !RING2){
            __builtin_amdgcn_global_load_lds(   // h1 ping-pong: L3-coherent read
              (const __attribute__((address_space(1))) void*)src,
              (__attribute__((address_space(3))) void*)&sm.a[bb][i*512], 16, 0, 17);
          } else {
            __builtin_amdgcn_global_load_lds(
              (const __attribute__((address_space(1))) void*)src,
              (__attribute__((address_space(3))) void*)&sm.a[bb][i*512], 16, 0, 0);
          }
        }
      }
    };

    const bool pre = (LAYER == 1) && (t > 0);   // chunks 0,1 issued inside prev barrier
    if (!pre) stage(0, 0, 512, 6, A1, A2);
    __syncthreads();

    #pragma unroll
    for (int ch = 0; ch < NCH; ch++){
      const int bb = ch & 1;
      const int kw = ((KTOT - ch*512) >= 512) ? 512 : (KTOT - ch*512);
      if (ch + 1 < NCH && !(pre && ch == 0)){
        const int kwn = ((KTOT - (ch+1)*512) >= 512) ? 512 : (KTOT - (ch+1)*512);
        stage(bb ^ 1, ch+1, kwn, (kwn == 512) ? 6 : 4, A1, A2);
      }
      const int UPR  = kw >> 3;                 // 16B units per row
      const int nksl = kw >> 6;                 // ks steps handled by this wave (kstc/2)
      #pragma unroll
      for (int ksl = 0; ksl < nksl; ksl++){
        const int klocal = ksl*2 + ksh;
        const int jf = ch*8 + ksl;              // global kst>>1 — compile-time
        const int unit = klocal*4 + lg;
        #pragma unroll
        for (int mi = 0; mi < 2; mi++){
          const int arow = mi*16 + lrow;
          bf16x8 af = *(const bf16x8*)&sm.a[bb][(arow*UPR + (unit ^ (arow & 7)))*8];
          acc2[mi] = __builtin_amdgcn_mfma_f32_16x16x32_bf16(af, wreg[jf], acc2[mi], 0, 0, 0);
        }
      }
      __syncthreads();
    }

    {   // write partials: [ksh][gate*32 + row][col]
      #pragma unroll
      for (int mi = 0; mi < 2; mi++)
        #pragma unroll
        for (int r = 0; r < 4; r++){
          const int row2 = mi*16 + lg*4 + r;
          sm.e[ksh][(cgi*32 + row2)*18 + lrow] = acc2[mi][r];
        }
    }
    __syncthreads();
    {
      float zi = sm.e[0][(0*32+erow)*18 + ejj] + sm.e[1][(0*32+erow)*18 + ejj];
      float zf = sm.e[0][(1*32+erow)*18 + ejj] + sm.e[1][(1*32+erow)*18 + ejj];
      float zo = sm.e[0][(2*32+erow)*18 + ejj] + sm.e[1][(2*32+erow)*18 + ejj];
      float zg = sm.e[0][(3*32+erow)*18 + ejj] + sm.e[1][(3*32+erow)*18 + ejj];
      zi += bias[0*Hn + J]; zf += bias[1*Hn + J];
      zo += bias[2*Hn + J]; zg += bias[3*Hn + J];
      const float gi = 1.f/(1.f + __expf(-zi));
      const float gf = 1.f/(1.f + __expf(-zf));
      const float go = 1.f/(1.f + __expf(-zo));
      const float gg = tanhf(zg);
      creg = gf * creg + gi * gg;
      const float hn = go * tanhf(creg);
      // publish h at agent scope (sc1 -> L3), packed 2x bf16 per dword
      const unsigned hu   = (unsigned)f2bf(hn);
      const unsigned mate = (unsigned)__shfl_xor((int)hu, 1);
      if ((l & 1) == 0){
        const unsigned pk = hu | (mate << 16);
        __hip_atomic_store((unsigned*)(hout + idx), pk,
                           __ATOMIC_RELAXED, __HIP_MEMORY_SCOPE_AGENT);
      }
      if (t == SEQn-1){
        cst[idx] = creg;                 // layer handoff / final output (kernel boundary)
        if (LAYER == 1) hf_out[idx] = hn;
      }
    }

    if (t + 1 < SEQn){
      // ---- grid barrier with in-barrier prefetch (L1 only) ----
      __syncthreads();                   // drains vmcnt: h-publishes at L3; sm free
      if (tid == 0)
        __hip_atomic_fetch_add(&bar[t], 1u, __ATOMIC_RELAXED, __HIP_MEMORY_SCOPE_AGENT);
      if constexpr (LAYER == 1){
        // next step's A1 = h0 ring slot t+2: written by the PREVIOUS kernel -> stable;
        // chunks 0,1 are entirely kg < K1, so the A2 arg is never dereferenced.
        const unsigned short* A1n = hring + (size_t)(t+2)*BH;
        stage(0, 0, 512, 6, A1n, A1n);
        stage(1, 1, 512, 6, A1n, A1n);
      }
      if (tid == 0){
        while (__hip_atomic_load(&bar[t], __ATOMIC_RELAXED, __HIP_MEMORY_SCOPE_AGENT) < GN)
          __builtin_amdgcn_s_sleep(1);
      }
      __syncthreads();                   // exit: also drains the prefetch issued above
    }
  }
}

// ---- final FC + copy h,c to d_out ----
__global__ __launch_bounds__(256)
void fc_out_kernel(const float* __restrict__ hf, const float* __restrict__ cst,
                   const float* __restrict__ fcw, const float* __restrict__ fcb,
                   float* __restrict__ dout){
  __shared__ float hrow[Hn];
  const int b = blockIdx.x, tid = threadIdx.x;
  for (int i = tid; i < Hn; i += 256) hrow[i] = hf[(size_t)b*Hn + i];
  __syncthreads();
  if (tid < PRED){
    float a = fcb[tid];
    for (int k = 0; k < Hn; k++) a += hrow[k] * fcw[(size_t)k*PRED + tid];
    dout[(size_t)b*PRED + tid] = tanhf(a);
  }
  for (int i = tid; i < Hn; i += 256){
    dout[Bsz*PRED + (size_t)b*Hn + i] = hf[(size_t)b*Hn + i];
    dout[Bsz*PRED + (size_t)Bsz*Hn + (size_t)b*Hn + i] = cst[(size_t)b*Hn + i];
  }
}

extern "C" void kernel_launch(void* const* d_in, const int* in_sizes, int n_in,
                              void* d_out, int out_size, void* d_ws, size_t ws_size,
                              hipStream_t stream){
  const float* x   = (const float*)d_in[0];
  const float* W0  = (const float*)d_in[1];
  const float* b0  = (const float*)d_in[2];
  const float* W1  = (const float*)d_in[3];
  const float* b1  = (const float*)d_in[4];
  const float* fcw = (const float*)d_in[5];
  const float* fcb = (const float*)d_in[6];
  float* dout = (float*)d_out;

  char* p = (char*)d_ws;
  auto alloc = [&](size_t bytes)->void*{
    void* r = (void*)p; p += (bytes + 255) & ~(size_t)255; return r;
  };
  // base footprint ~103.5 MB (proven); +67 MB h1 ring only if workspace allows
  unsigned short* xp   = (unsigned short*)alloc((size_t)SEQn*Bsz*NUMS*2);      // 8.4 MB
  unsigned short* Wpk0 = (unsigned short*)alloc((size_t)256*36*64*8*2);        // 9.4 MB
  unsigned short* Wpk1 = (unsigned short*)alloc((size_t)256*64*64*8*2);        // 16.8 MB
  unsigned short* H0   = (unsigned short*)alloc((size_t)(SEQn+1)*BH*2);        // 67.4 MB
  float* cst = (float*)alloc((size_t)BH*4);                                    // 0.5 MB
  float* hf  = (float*)alloc((size_t)BH*4);                                    // 0.5 MB
  unsigned* bars = (unsigned*)alloc((size_t)512*sizeof(unsigned));             // 2 KB

  const bool big = ws_size >= (size_t)176*1024*1024;   // room for write-once h1 ring?
  unsigned short* h1b;
  if (big) h1b = (unsigned short*)alloc((size_t)SEQn*BH*2);                    // 67.1 MB
  else     h1b = (unsigned short*)alloc((size_t)2*BH*2);                       // 0.5 MB

  pack_x_kernel<<<dim3(SEQn/64, NUMS/64, Bsz), dim3(256), 0, stream>>>(x, xp);
  pack_w_kernel<<<dim3((256*36*64 + 255)/256), dim3(256), 0, stream>>>(W0, Wpk0, 36, 0, 1);
  pack_w_kernel<<<dim3((256*64*64 + 255)/256), dim3(256), 0, stream>>>(W1, Wpk1, 64, 0, 1);
  zero_kernel<<<dim3((Bsz*Hn + 255)/256), dim3(256), 0, stream>>>(H0, cst, bars);

  // layer 0: ONE persistent launch, 256 grid-barriered steps (K = 128 + 1024)
  persist_kernel<128, 1152, 0, false><<<dim3(GN), dim3(512), 0, stream>>>(
      xp, H0, nullptr, Wpk0, b0, cst, nullptr, bars);

  // layer 1: ONE persistent launch (K = 1024 + 1024)
  if (big){
    persist_kernel<1024, 2048, 1, true><<<dim3(GN), dim3(512), 0, stream>>>(
        nullptr, H0, h1b, Wpk1, b1, cst, hf, bars + 256);
  } else {
    persist_kernel<1024, 2048, 1, false><<<dim3(GN), dim3(512), 0, stream>>>(
        nullptr, H0, h1b, Wpk1, b1, cst, hf, bars + 256);
  }

  fc_out_kernel<<<dim3(Bsz), dim3(256), 0, stream>>>(hf, cst, fcw, fcb, dout);
}

// Round 6
// 3527.687 us; speedup vs baseline: 2.8587x; 1.6615x over previous
//
#include <hip/hip_runtime.h>
#include <stdint.h>

#define Bsz  128
#define NUMS 128
#define SEQn 256
#define Hn   1024
#define PRED 96
#define G4H  4096
#define GN   256            // persistent grid: 256 blocks = 64 nb x 4 mb (1 per CU)
#define BH   ((size_t)Bsz*Hn)

typedef __attribute__((ext_vector_type(8))) short bf16x8;
typedef __attribute__((ext_vector_type(4))) float f32x4;

template<int N> struct IC { static constexpr int value = N; };

__device__ __forceinline__ unsigned short f2bf(float x){
  union { float f; unsigned u; } v; v.f = x;
  return (unsigned short)((v.u + 0x7FFFu + ((v.u >> 16) & 1u)) >> 16);
}
__device__ __forceinline__ float bf2f(unsigned short s){
  union { unsigned u; float f; } v; v.u = ((unsigned)s) << 16; return v.f;
}

// ---- pack x: [B][NUMS][SEQ] f32 -> xp [SEQ][B][NUMS] bf16 (LDS transpose) ----
__global__ void pack_x_kernel(const float* __restrict__ x, unsigned short* __restrict__ xp){
  __shared__ float tile[64][65];
  const int t0 = blockIdx.x * 64, n0 = blockIdx.y * 64, b = blockIdx.z;
  const int tid = threadIdx.x;
  const int c = tid & 63, r = tid >> 6;
  #pragma unroll
  for (int i = 0; i < 16; i++){
    int n = r + i*4;
    tile[n][c] = x[((size_t)b*NUMS + n0 + n)*SEQn + t0 + c];
  }
  __syncthreads();
  #pragma unroll
  for (int i = 0; i < 16; i++){
    int t = r + i*4;
    xp[((size_t)(t0+t)*Bsz + b)*NUMS + n0 + c] = f2bf(tile[c][t]);
  }
}

// ---- pack W rows into MFMA B-frag order: Wpk[cgg][kof+kst][lane][8] ----
__global__ void pack_w_kernel(const float* __restrict__ W, unsigned short* __restrict__ Wpk,
                              int KST, int row_off, int kstride, int kof){
  const int u = blockIdx.x * blockDim.x + threadIdx.x;
  if (u >= 256*KST*64) return;
  const int lane = u & 63;
  const int kst  = (u >> 6) % KST;
  const int cgg  = (u >> 6) / KST;
  const int nb = cgg >> 2, gate = cgg & 3;
  const int col = gate*Hn + nb*16 + (lane & 15);
  const int kbase = row_off + kst*32 + (lane >> 4)*8;
  unsigned short tmp[8];
  #pragma unroll
  for (int e = 0; e < 8; e++) tmp[e] = f2bf(W[(size_t)(kbase+e)*G4H + col]);
  ((ulonglong2*)Wpk)[(size_t)(cgg*kstride + kof + kst)*64 + lane] = *(const ulonglong2*)tmp;
}

__global__ void zero_kernel(unsigned short* __restrict__ h0, float* __restrict__ c,
                            unsigned* __restrict__ bars){
  int i = blockIdx.x*256 + threadIdx.x;
  if (i < Bsz*Hn){ h0[i] = 0; c[i] = 0.0f; }
  if (i < 512) bars[i] = 0u;
}

// ---- persistent LSTM layer, W resident in VGPRs across all 256 steps ----
// grid = 256 blocks (1/CU), 512 thr = 8 waves = 4 gates x 2 K-parities.
// Per-wave W: KST_TOT/2 bf16x8 frags (72 VGPR L0 / 128 VGPR L1); all wreg indices
// compile-time (tagged-lambda chunk expansion) + asm keepalive per t-iteration
// so the allocator cannot demote wreg to scratch (round-4 failure: VGPR=112).
// K layout: [region1: h, stride K1=1024] [region2: stride S2].
//   LAYER=0: region1 = h0_{t-1} (ring slot t), region2 = xp_t (static input,
//            prefetched under the grid barrier into xb).
//   LAYER=1: region1 = h0_t (ring slot t+1, stable -> in-barrier prefetch),
//            region2 = h1_{t-1} (RING2: write-once ring; else aux=17 ping-pong).
// c lives in ONE register per thread across all 256 steps.
template<int K1, int S2, int KTOT, int LAYER, bool RING2>
__global__ __launch_bounds__(512, 2)
void persist_kernel(const unsigned short* __restrict__ xpp,
                    unsigned short* __restrict__ hring,
                    unsigned short* __restrict__ h1b,
                    const unsigned short* __restrict__ Wpk,
                    const float* __restrict__ bias,
                    float* __restrict__ cst,
                    float* __restrict__ hf_out,
                    unsigned* __restrict__ bar)
{
  constexpr int KST_TOT = KTOT/32;
  constexpr int HALF = KST_TOT/2;
  constexpr int NCH = (KTOT + 511)/512;
  __shared__ union SM {
    struct { unsigned short a[2][32*512]; unsigned short xb[32*128]; } s;  // 64KB + 8KB
    float e[2][4*32*18];                                                   // 18.4KB overlay
  } sm;
  const int tid = threadIdx.x;
  const int w = tid >> 6, l = tid & 63;
  const int blk = blockIdx.x;
  const int q = blk >> 3;
  const int nb = (blk & 7)*8 + (q & 7);   // XCD (blk&7) owns 8 consecutive nb
  const int mb = q >> 3;                  // 0..3, 32 rows each
  const int ksh = w & 1, cgi = w >> 1;    // K-parity, gate
  const int cgg = nb*4 + cgi;
  const int lrow = l & 15, lg = l >> 4;

  // ---- W -> registers, once ----
  bf16x8 wreg[HALF];
  #pragma unroll
  for (int j = 0; j < HALF; j++)
    wreg[j] = *(const bf16x8*)(Wpk + ((size_t)(cgg*KST_TOT + 2*j + ksh)*64 + l)*8);

  // fixed per-thread epilogue element; c stays in a register across steps
  const int erow = tid >> 4, ejj = tid & 15;
  const int R = mb*32 + erow;
  const int J = nb*16 + ejj;
  const size_t idx = (size_t)R*Hn + J;
  float creg = (LAYER == 0) ? 0.f : cst[idx];

  for (int t = 0; t < SEQn; ++t){
    // keepalive: force wreg to stay materialized in VGPRs across the loop
    #pragma unroll
    for (int j = 0; j < HALF; j++) asm volatile("" : "+v"(wreg[j]));

    const unsigned short* A1;
    const unsigned short* A2;
    unsigned short* hout;
    if (LAYER == 0){
      A1   = hring + (size_t)t*BH;                           // h0_{t-1}
      A2   = xpp + (size_t)t*Bsz*NUMS;                       // x_t (static)
      hout = hring + (size_t)(t+1)*BH;
    } else {
      A1   = hring + (size_t)(t+1)*BH;                       // h0_t (prev kernel output)
      A2   = (t == 0) ? (hring + (size_t)SEQn*BH)
                      : (h1b + (size_t)(RING2 ? (t-1) : ((t-1)&1))*BH);
      hout = h1b + (size_t)(RING2 ? t : (t&1))*BH;
    }

    f32x4 acc2[2] = {{0.f,0.f,0.f,0.f},{0.f,0.f,0.f,0.f}};

    auto stage = [&](int ch, int kw, int lu,
                     const unsigned short* A1p, const unsigned short* A2p){
      unsigned short* dst = (LAYER == 0 && ch == NCH-1) ? sm.s.xb : sm.s.a[ch & 1];
      const int nissue = kw >> 4;                 // (32 rows * kw * 2B) / 1024B
      for (int i = w; i < nissue; i += 8){
        const int s = i*64 + l;
        const int row = s >> lu;
        const int uu  = s & ((1 << lu) - 1);
        const int ku  = uu ^ (row & 7);
        const int kg  = ch*512 + ku*8;
        const int Rr  = mb*32 + row;
        if (kg < K1){
          const unsigned short* src = A1p + (size_t)Rr*K1 + kg;
          __builtin_amdgcn_global_load_lds(
            (const __attribute__((address_space(1))) void*)src,
            (__attribute__((address_space(3))) void*)&dst[i*512], 16, 0, 0);
        } else {
          const unsigned short* src = A2p + (size_t)Rr*S2 + (kg - K1);
          if constexpr (LAYER == 1 && !RING2){
            __builtin_amdgcn_global_load_lds(   // h1 ping-pong: L3-coherent read
              (const __attribute__((address_space(1))) void*)src,
              (__attribute__((address_space(3))) void*)&dst[i*512], 16, 0, 17);
          } else {
            __builtin_amdgcn_global_load_lds(
              (const __attribute__((address_space(1))) void*)src,
              (__attribute__((address_space(3))) void*)&dst[i*512], 16, 0, 0);
          }
        }
      }
    };

    const bool pre01 = (LAYER == 1) && (t > 0);   // chunks 0,1 prefetched in barrier
    const bool preX  = (LAYER == 0) && (t > 0);   // xb chunk prefetched in barrier
    if (!pre01){
      constexpr int kw0 = (KTOT >= 512) ? 512 : KTOT;
      stage(0, kw0, (kw0 == 512) ? 6 : 4, A1, A2);
    }
    __syncthreads();

    // ---- chunk bodies with fully compile-time wreg indices (tagged lambda) ----
    auto do_chunk = [&](auto CHC){
      constexpr int ch = decltype(CHC)::value;
      if constexpr (ch < NCH){
        constexpr int kw = ((KTOT - ch*512) >= 512) ? 512 : (KTOT - ch*512);
        if constexpr (ch + 1 < NCH){
          constexpr int kwn = ((KTOT - (ch+1)*512) >= 512) ? 512 : (KTOT - (ch+1)*512);
          const bool skip = (pre01 && (ch+1) == 1) || (preX && (ch+1) == NCH-1);
          if (!skip) stage(ch+1, kwn, (kwn == 512) ? 6 : 4, A1, A2);
        }
        constexpr int UPR  = kw >> 3;
        constexpr int nksl = kw >> 6;
        const unsigned short* abase = (LAYER == 0 && ch == NCH-1) ? sm.s.xb
                                                                  : sm.s.a[ch & 1];
        #pragma unroll
        for (int ksl = 0; ksl < nksl; ksl++){
          const int klocal = ksl*2 + ksh;
          const int unit = klocal*4 + lg;
          bf16x8 af0 = *(const bf16x8*)&abase[((lrow     )*UPR + (unit ^ (lrow & 7)))*8];
          bf16x8 af1 = *(const bf16x8*)&abase[((lrow + 16)*UPR + (unit ^ (lrow & 7)))*8];
          acc2[0] = __builtin_amdgcn_mfma_f32_16x16x32_bf16(af0, wreg[ch*8 + ksl], acc2[0], 0, 0, 0);
          acc2[1] = __builtin_amdgcn_mfma_f32_16x16x32_bf16(af1, wreg[ch*8 + ksl], acc2[1], 0, 0, 0);
        }
        __syncthreads();
      }
    };
    do_chunk(IC<0>{}); do_chunk(IC<1>{}); do_chunk(IC<2>{}); do_chunk(IC<3>{});

    {   // write partials: [ksh][gate*32 + row][col]
      #pragma unroll
      for (int mi = 0; mi < 2; mi++)
        #pragma unroll
        for (int r = 0; r < 4; r++){
          const int row2 = mi*16 + lg*4 + r;
          sm.e[ksh][(cgi*32 + row2)*18 + lrow] = acc2[mi][r];
        }
    }
    __syncthreads();
    {
      float zi = sm.e[0][(0*32+erow)*18 + ejj] + sm.e[1][(0*32+erow)*18 + ejj];
      float zf = sm.e[0][(1*32+erow)*18 + ejj] + sm.e[1][(1*32+erow)*18 + ejj];
      float zo = sm.e[0][(2*32+erow)*18 + ejj] + sm.e[1][(2*32+erow)*18 + ejj];
      float zg = sm.e[0][(3*32+erow)*18 + ejj] + sm.e[1][(3*32+erow)*18 + ejj];
      zi += bias[0*Hn + J]; zf += bias[1*Hn + J];
      zo += bias[2*Hn + J]; zg += bias[3*Hn + J];
      const float gi = 1.f/(1.f + __expf(-zi));
      const float gf = 1.f/(1.f + __expf(-zf));
      const float go = 1.f/(1.f + __expf(-zo));
      const float gg = tanhf(zg);
      creg = gf * creg + gi * gg;
      const float hn = go * tanhf(creg);
      // publish h at agent scope (sc1 -> L3), packed 2x bf16 per dword
      const unsigned hu   = (unsigned)f2bf(hn);
      const unsigned mate = (unsigned)__shfl_xor((int)hu, 1);
      if ((l & 1) == 0){
        const unsigned pk = hu | (mate << 16);
        __hip_atomic_store((unsigned*)(hout + idx), pk,
                           __ATOMIC_RELAXED, __HIP_MEMORY_SCOPE_AGENT);
      }
      if (t == SEQn-1){
        cst[idx] = creg;                 // layer handoff / final output (kernel boundary)
        if (LAYER == 1) hf_out[idx] = hn;
      }
    }

    if (t + 1 < SEQn){
      // ---- grid barrier with in-barrier prefetch ----
      __syncthreads();                   // drains vmcnt: h-publishes at L3; sm free
      if (tid == 0)
        __hip_atomic_fetch_add(&bar[t], 1u, __ATOMIC_RELAXED, __HIP_MEMORY_SCOPE_AGENT);
      if constexpr (LAYER == 1){
        // next step's region1 = h0 ring slot t+2: written by the PREVIOUS kernel ->
        // stable; chunks 0,1 are entirely kg < K1, so A2 is never dereferenced.
        const unsigned short* A1n = hring + (size_t)(t+2)*BH;
        stage(0, 512, 6, A1n, A1n);
        stage(1, 512, 6, A1n, A1n);
      } else {
        // next step's region2 = xp_{t+1}: static input -> prefetch into xb.
        stage(NCH-1, 128, 4, A1, xpp + (size_t)(t+1)*Bsz*NUMS);
      }
      if (tid == 0){
        while (__hip_atomic_load(&bar[t], __ATOMIC_RELAXED, __HIP_MEMORY_SCOPE_AGENT) < GN)
          __builtin_amdgcn_s_sleep(1);
      }
      __syncthreads();                   // exit: also drains the prefetch issued above
    }
  }
}

// ---- final FC + copy h,c to d_out ----
__global__ __launch_bounds__(256)
void fc_out_kernel(const float* __restrict__ hf, const float* __restrict__ cst,
                   const float* __restrict__ fcw, const float* __restrict__ fcb,
                   float* __restrict__ dout){
  __shared__ float hrow[Hn];
  const int b = blockIdx.x, tid = threadIdx.x;
  for (int i = tid; i < Hn; i += 256) hrow[i] = hf[(size_t)b*Hn + i];
  __syncthreads();
  if (tid < PRED){
    float a = fcb[tid];
    for (int k = 0; k < Hn; k++) a += hrow[k] * fcw[(size_t)k*PRED + tid];
    dout[(size_t)b*PRED + tid] = tanhf(a);
  }
  for (int i = tid; i < Hn; i += 256){
    dout[Bsz*PRED + (size_t)b*Hn + i] = hf[(size_t)b*Hn + i];
    dout[Bsz*PRED + (size_t)Bsz*Hn + (size_t)b*Hn + i] = cst[(size_t)b*Hn + i];
  }
}

extern "C" void kernel_launch(void* const* d_in, const int* in_sizes, int n_in,
                              void* d_out, int out_size, void* d_ws, size_t ws_size,
                              hipStream_t stream){
  const float* x   = (const float*)d_in[0];
  const float* W0  = (const float*)d_in[1];
  const float* b0  = (const float*)d_in[2];
  const float* W1  = (const float*)d_in[3];
  const float* b1  = (const float*)d_in[4];
  const float* fcw = (const float*)d_in[5];
  const float* fcb = (const float*)d_in[6];
  float* dout = (float*)d_out;

  char* p = (char*)d_ws;
  auto alloc = [&](size_t bytes)->void*{
    void* r = (void*)p; p += (bytes + 255) & ~(size_t)255; return r;
  };
  // base footprint ~103.5 MB (proven); +67 MB h1 ring only if workspace allows
  unsigned short* xp   = (unsigned short*)alloc((size_t)SEQn*Bsz*NUMS*2);      // 8.4 MB
  unsigned short* Wpk0 = (unsigned short*)alloc((size_t)256*36*64*8*2);        // 9.4 MB
  unsigned short* Wpk1 = (unsigned short*)alloc((size_t)256*64*64*8*2);        // 16.8 MB
  unsigned short* H0   = (unsigned short*)alloc((size_t)(SEQn+1)*BH*2);        // 67.4 MB
  float* cst = (float*)alloc((size_t)BH*4);                                    // 0.5 MB
  float* hf  = (float*)alloc((size_t)BH*4);                                    // 0.5 MB
  unsigned* bars = (unsigned*)alloc((size_t)512*sizeof(unsigned));             // 2 KB

  const bool big = ws_size >= (size_t)176*1024*1024;   // room for write-once h1 ring?
  unsigned short* h1b;
  if (big) h1b = (unsigned short*)alloc((size_t)SEQn*BH*2);                    // 67.1 MB
  else     h1b = (unsigned short*)alloc((size_t)2*BH*2);                       // 0.5 MB

  pack_x_kernel<<<dim3(SEQn/64, NUMS/64, Bsz), dim3(256), 0, stream>>>(x, xp);
  // W0 packed K order: [h rows 128..1151 -> kst 0..31][x rows 0..127 -> kst 32..35]
  pack_w_kernel<<<dim3((256*32*64 + 255)/256), dim3(256), 0, stream>>>(W0, Wpk0, 32, 128, 36, 0);
  pack_w_kernel<<<dim3((256*4*64  + 255)/256), dim3(256), 0, stream>>>(W0, Wpk0,  4,   0, 36, 32);
  // W1: rows 0..1023 = h0-part, 1024..2047 = h1-part (natural order)
  pack_w_kernel<<<dim3((256*64*64 + 255)/256), dim3(256), 0, stream>>>(W1, Wpk1, 64, 0, 64, 0);
  zero_kernel<<<dim3((Bsz*Hn + 255)/256), dim3(256), 0, stream>>>(H0, cst, bars);

  // layer 0: ONE persistent launch, 256 grid-barriered steps (K = [h 1024 | x 128])
  persist_kernel<1024, NUMS, 1152, 0, false><<<dim3(GN), dim3(512), 0, stream>>>(
      xp, H0, nullptr, Wpk0, b0, cst, nullptr, bars);

  // layer 1: ONE persistent launch (K = [h0 1024 | h1 1024])
  if (big){
    persist_kernel<1024, Hn, 2048, 1, true><<<dim3(GN), dim3(512), 0, stream>>>(
        nullptr, H0, h1b, Wpk1, b1, cst, hf, bars + 256);
  } else {
    persist_kernel<1024, Hn, 2048, 1, false><<<dim3(GN), dim3(512), 0, stream>>>(
        nullptr, H0, h1b, Wpk1, b1, cst, hf, bars + 256);
  }

  fc_out_kernel<<<dim3(Bsz), dim3(256), 0, stream>>>(hf, cst, fcw, fcb, dout);
}